// Round 3
// baseline (324.691 us; speedup 1.0000x reference)
//
#include <hip/hip_runtime.h>
#include <stdint.h>

#define VOCAB 28996
#define EMBED 512
#define NROWS 8192
#define VPAD  29056  /* 227*128 — same workspace layout as the proven round-0 kernel */
#define LOG2E 1.4426950408889634f
#define WSCALE 16.0f
#define INV_WSCALE_L2E (LOG2E / 16.0f)

typedef __attribute__((ext_vector_type(4)))  int   i32x4;
typedef __attribute__((ext_vector_type(8)))  int   i32x8;
typedef __attribute__((ext_vector_type(16))) float f32x16;

__device__ __forceinline__ void gload_lds16(const void* g, void* l) {
  __builtin_amdgcn_global_load_lds(
      (__attribute__((address_space(1))) const void*)g,
      (__attribute__((address_space(3))) void*)l, 16, 0, 0);
}

// pack 4 floats -> 4 x fp8 e4m3 (OCP, RNE, saturating) in one i32
// NOTE: saturating cvt never produces the 0x7F/0xFF NaN encodings, so every
// byte of xb/wb is a finite fp8 value — safe to feed any of it to MFMA.
__device__ __forceinline__ int pk_fp8x4(float a, float b, float c, float d) {
  int r = __builtin_amdgcn_cvt_pk_fp8_f32(a, b, 0, false);
  r = __builtin_amdgcn_cvt_pk_fp8_f32(c, d, r, true);
  return r;
}

// ---- fused prep (IDENTICAL to the harness-verified round-0 kernel) ----
// blocks [0,7264): W   (VPAD*512/8/256 = 7264)
// blocks [7264,9312): x (8192*512/8/256 = 2048)
// blocks [9312,11360): py (1 wave/row, 4 rows/block)
// blocks [11360,11392): zero sg
__global__ void __launch_bounds__(256)
prep_kernel(const float* __restrict__ x, const float* __restrict__ W,
            const float* __restrict__ b, const int* __restrict__ y,
            int* __restrict__ xb, int* __restrict__ wb,
            float* __restrict__ py, float* __restrict__ sg) {
  const int bid = blockIdx.x;
  if (bid < 7264) {                        // ---- cvt W*16 -> fp8 ----
    int i = (bid * 256 + threadIdx.x) * 8; // float index; VK multiple of 8
    const int VK = VOCAB * EMBED;
    int2 o;
    if (i < VK) {
      float4 v0 = *(const float4*)(W + i);
      float4 v1 = *(const float4*)(W + i + 4);
      o.x = pk_fp8x4(v0.x * WSCALE, v0.y * WSCALE, v0.z * WSCALE, v0.w * WSCALE);
      o.y = pk_fp8x4(v1.x * WSCALE, v1.y * WSCALE, v1.z * WSCALE, v1.w * WSCALE);
    } else { o.x = 0; o.y = 0; }
    *(int2*)(wb + i / 4) = o;
  } else if (bid < 9312) {                 // ---- cvt x -> fp8 ----
    int i = ((bid - 7264) * 256 + threadIdx.x) * 8;
    float4 v0 = *(const float4*)(x + i);
    float4 v1 = *(const float4*)(x + i + 4);
    int2 o;
    o.x = pk_fp8x4(v0.x, v0.y, v0.z, v0.w);
    o.y = pk_fp8x4(v1.x, v1.y, v1.z, v1.w);
    *(int2*)(xb + i / 4) = o;
  } else if (bid < 11360) {                // ---- py: e^{x.W[y]+b[y]}, fp32 exact ----
    const int row  = ((bid - 9312) * 256 + threadIdx.x) >> 6;
    const int lane = threadIdx.x & 63;
    const int yr = y[row];
    const float4* xr = (const float4*)(x + (size_t)row * EMBED);
    const float4* wr = (const float4*)(W + (size_t)yr * EMBED);
    float d = 0.f;
#pragma unroll
    for (int t = 0; t < 2; ++t) {
      float4 a = xr[lane * 2 + t], c = wr[lane * 2 + t];
      d += a.x * c.x + a.y * c.y + a.z * c.z + a.w * c.w;
    }
#pragma unroll
    for (int m = 1; m < 64; m <<= 1) d += __shfl_xor(d, m);
    if (lane == 0) py[row] = __expf(d + b[yr]);
  } else {                                 // ---- zero sg ----
    int i = (bid - 11360) * 256 + threadIdx.x;
    sg[i] = 0.f;
  }
}

// ---- fused GEMM (16*logits = x . (16W)^T, MX-fp8 32x32x64) + row-sum exp ----
// 256x256 tile, BK=128, 8 waves 2x4, wave tile 128x64 = 4x2 of 32x32
// (acc = 128 regs). LDS: 2 dbuf x (lA 32K + lB 32K) = 128 KiB, 1 block/CU.
//
// 8-PHASE FINE-INTERLEAVED K-LOOP (T3+T4+T5, port of the m201 template):
// per K-tile, 4 phases (one per mi quadrant):
//   { ds_read af[mi] (4 x b128) [+ bq (8 x b128) in phase 0];
//     issue 4 staging loads for kt+1 (phases 0: A, 1: B);
//     s_barrier;                       // align waves, do NOT drain vmcnt
//     s_waitcnt lgkmcnt(0); sched_barrier(0);
//     setprio(1); 4 x mfma_scale; setprio(0);
//     s_barrier; }
// vmcnt(0) ONLY at the K-tile gate: the only outstanding VMEM there are the
// current buffer's 8 loads, issued in the previous K-tile's phases 0-1 —
// >= 2.5 phases (~700+ cy) of compute cover, i.e. a counted wait, never a
// cold drain (except the one prologue stage).
// Race audit: every wave's ds_reads of buf^1 drain at its own phase-3
// lgkmcnt(0), which precedes the gate barrier -> staging into buf^1 after
// the gate is WAR-safe; ds_reads can't hoist above s_barrier (memory fence);
// MFMA hoisting past the asm lgkmcnt is fenced by sched_barrier(0) (rule 18).
//
// LDS layout identical to round-0: row = 128 B, 16B-chunk XOR swizzle
// (chunk J of row R at R*128 + ((J^(R&7))*16)); staging destination linear
// for global_load_lds with pre-swizzled global source.
// Tail tile (grid.y=114 covers 29184 cols > VPAD): B staging row clamped to
// VPAD-8 — clamped rows re-read finite fp8, and bias=-1e30 for col>=VOCAB
// makes their exp contribution exactly 0.
__global__ void __launch_bounds__(512, 2)
gemm_stats_kernel(const uint8_t* __restrict__ xb, const uint8_t* __restrict__ wb,
                  const float* __restrict__ bias, float* __restrict__ sg) {
  __shared__ uint8_t lA[2][256 * 128];
  __shared__ uint8_t lB[2][256 * 128];

  const int tid  = threadIdx.x;
  const int lane = tid & 63;
  const int w    = tid >> 6;       // wave 0..7
  const int l31  = lane & 31;
  const int h    = lane >> 5;      // k-half for 32x32 operands
  const int kx   = lane & 7;       // swizzle key (fragment row & 7 == lane & 7)
  const int wr   = (w >> 2) * 128; // wave row offset in tile (2 row-groups)
  const int wc   = (w & 3) * 64;   // wave col offset in tile (4 col-groups)
  const int rowBase = blockIdx.x * 256;  // x rows     (grid.x = 32)
  const int colBase = blockIdx.y * 256;  // vocab cols (grid.y = 114)

  const int srow = lane >> 3;                 // 0..7 (row within 8-row chunk)
  const int skel = (kx ^ srow) * 16;          // swizzled byte offset in row

  f32x16 acc[4][2];
#pragma unroll
  for (int i = 0; i < 4; ++i)
#pragma unroll
    for (int j = 0; j < 2; ++j)
#pragma unroll
      for (int r = 0; r < 16; ++r) acc[i][j][r] = 0.f;

  // staging: chunk c (8 rows); this lane covers global row c*8+srow,
  // global 16B slot (kx^srow) -> LDS linear lane*16 within the chunk.
  // prologue: stage K-tile 0 into buf 0 (cold, once per block)
#pragma unroll
  for (int t = 0; t < 4; ++t) {
    const int c = w * 4 + t;
    const int ar = rowBase + c * 8;
    int br = colBase + c * 8;
    if (br > VPAD - 8) br = VPAD - 8;
    gload_lds16(xb + (size_t)(ar + srow) * EMBED + skel, &lA[0][c * 1024]);
    gload_lds16(wb + (size_t)(br + srow) * EMBED + skel, &lB[0][c * 1024]);
  }

  const int aBase = (wr + l31) * 128;        // mi=0 fragment row base
  const int bBase = (wc + l31) * 128;        // ni=0 fragment row base

#pragma unroll
  for (int kt = 0; kt < 4; ++kt) {
    const int cur = kt & 1;
    // ---- K-tile gate: counted-by-construction vmcnt, then barrier ----
    asm volatile("s_waitcnt vmcnt(0)" ::: "memory");
    __builtin_amdgcn_sched_barrier(0);
    __builtin_amdgcn_s_barrier();

    const uint8_t* __restrict__ Ab = lA[cur];
    const uint8_t* __restrict__ Bb = lB[cur];
    uint8_t* __restrict__ An = lA[cur ^ 1];
    uint8_t* __restrict__ Bn = lB[cur ^ 1];
    const int k1 = (kt + 1) * 128;

    i32x8 bq[2][2];
#pragma unroll
    for (int mi = 0; mi < 4; ++mi) {
      // ---- phase reads ----
      if (mi == 0) {
#pragma unroll
        for (int kk = 0; kk < 2; ++kk) {
          const int c0 = ((kk * 4 + h * 2) ^ kx) << 4;
          const int c1 = c0 ^ 16;
#pragma unroll
          for (int ni = 0; ni < 2; ++ni) {
            const uint8_t* bp = Bb + bBase + ni * 32 * 128;
            i32x4 lo = *(const i32x4*)(bp + c0);
            i32x4 hi = *(const i32x4*)(bp + c1);
            bq[kk][ni] = __builtin_shufflevector(lo, hi, 0, 1, 2, 3, 4, 5, 6, 7);
          }
        }
      }
      i32x8 af[2];
#pragma unroll
      for (int kk = 0; kk < 2; ++kk) {
        const int c0 = ((kk * 4 + h * 2) ^ kx) << 4;
        const int c1 = c0 ^ 16;
        const uint8_t* ap = Ab + aBase + mi * 32 * 128;
        i32x4 lo = *(const i32x4*)(ap + c0);
        i32x4 hi = *(const i32x4*)(ap + c1);
        af[kk] = __builtin_shufflevector(lo, hi, 0, 1, 2, 3, 4, 5, 6, 7);
      }
      // ---- phase staging: kt+1 A-chunks in phase 0, B-chunks in phase 1 ----
      if (kt < 3 && mi < 2) {
#pragma unroll
        for (int t = 0; t < 4; ++t) {
          const int c = w * 4 + t;
          if (mi == 0) {
            gload_lds16(xb + (size_t)(rowBase + c * 8 + srow) * EMBED + k1 + skel,
                        An + c * 1024);
          } else {
            int br = colBase + c * 8;
            if (br > VPAD - 8) br = VPAD - 8;
            gload_lds16(wb + (size_t)(br + srow) * EMBED + k1 + skel,
                        Bn + c * 1024);
          }
        }
      }
      // ---- align, drain own LDS reads, MFMA cluster under setprio ----
      __builtin_amdgcn_s_barrier();
      asm volatile("s_waitcnt lgkmcnt(0)" ::: "memory");
      __builtin_amdgcn_sched_barrier(0);
      __builtin_amdgcn_s_setprio(1);
#pragma unroll
      for (int kk = 0; kk < 2; ++kk)
#pragma unroll
        for (int ni = 0; ni < 2; ++ni)
          acc[mi][ni] = __builtin_amdgcn_mfma_scale_f32_32x32x64_f8f6f4(
              af[kk], bq[kk][ni], acc[mi][ni], 0, 0, 0, 0x7F7F7F7F, 0, 0x7F7F7F7F);
      __builtin_amdgcn_s_setprio(0);
      if (mi < 3) __builtin_amdgcn_s_barrier();  // phase-3 end barrier == next gate
    }
  }

  // ---- epilogue: s_row += sum_j exp(acc/16 + bias) ----
  // 32x32 C/D layout (m74/m101): col = lane&31, row = (reg&3)+8*(reg>>2)+4*h
  float bvl[2];
#pragma unroll
  for (int ni = 0; ni < 2; ++ni) {
    const int col = colBase + wc + ni * 32 + l31;
    bvl[ni] = (col < VOCAB) ? bias[col] * LOG2E : -1e30f;
  }

#pragma unroll
  for (int p = 0; p < 2; ++p) {            // p: 64-row half of the wave tile
    float sp[32];  // v = q*16 + reg, mi = p*2 + q
#pragma unroll
    for (int q = 0; q < 2; ++q)
#pragma unroll
      for (int r = 0; r < 16; ++r)
        sp[q * 16 + r] =
            exp2f(fmaf(acc[p * 2 + q][0][r], INV_WSCALE_L2E, bvl[0])) +
            exp2f(fmaf(acc[p * 2 + q][1][r], INV_WSCALE_L2E, bvl[1]));

    // stacking reduction over the 32 cols (xor 1..16 stays within the h-half);
    // ends with lane holding the full col-sum for value index v == (lane&31).
    float t1[16];
#pragma unroll
    for (int u = 0; u < 16; ++u) {
      float a = sp[2 * u]     + __shfl_xor(sp[2 * u],     1);
      float b = sp[2 * u + 1] + __shfl_xor(sp[2 * u + 1], 1);
      t1[u] = (l31 & 1) ? b : a;
    }
    float t2[8];
#pragma unroll
    for (int u = 0; u < 8; ++u) {
      float a = t1[2 * u]     + __shfl_xor(t1[2 * u],     2);
      float b = t1[2 * u + 1] + __shfl_xor(t1[2 * u + 1], 2);
      t2[u] = (l31 & 2) ? b : a;
    }
    float t3[4];
#pragma unroll
    for (int u = 0; u < 4; ++u) {
      float a = t2[2 * u]     + __shfl_xor(t2[2 * u],     4);
      float b = t2[2 * u + 1] + __shfl_xor(t2[2 * u + 1], 4);
      t3[u] = (l31 & 4) ? b : a;
    }
    float t4[2];
#pragma unroll
    for (int u = 0; u < 2; ++u) {
      float a = t3[2 * u]     + __shfl_xor(t3[2 * u],     8);
      float b = t3[2 * u + 1] + __shfl_xor(t3[2 * u + 1], 8);
      t4[u] = (l31 & 8) ? b : a;
    }
    {
      float a = t4[0] + __shfl_xor(t4[0], 16);
      float b = t4[1] + __shfl_xor(t4[1], 16);
      float ssum = (l31 & 16) ? b : a;
      const int v = l31;                 // q = v>>4, reg = v&15
      const int row = rowBase + wr + p * 64 + (v >> 4) * 32 +
                      (v & 3) + 8 * ((v & 15) >> 2) + 4 * h;
      atomicAdd(&sg[row], ssum);
    }
  }
}

// ---- final: loss = log(V+1) - mean(py/s)  (q-term ~7e-10, dropped) ----
__global__ void finalize_kernel(const float* __restrict__ sg, const float* __restrict__ py,
                                float* __restrict__ out) {
  __shared__ float red[256];
  float a = 0.f;
  for (int i = threadIdx.x; i < NROWS; i += 256)
    a += py[i] / sg[i];
  red[threadIdx.x] = a;
  __syncthreads();
  for (int st = 128; st > 0; st >>= 1) {
    if (threadIdx.x < st) red[threadIdx.x] += red[threadIdx.x + st];
    __syncthreads();
  }
  if (threadIdx.x == 0)
    out[0] = logf((float)(VOCAB + 1)) - red[0] * (1.f / (float)NROWS);
}

extern "C" void kernel_launch(void* const* d_in, const int* in_sizes, int n_in,
                              void* d_out, int out_size, void* d_ws, size_t ws_size,
                              hipStream_t stream) {
  const float* x = (const float*)d_in[0];
  const int*   y = (const int*)d_in[1];
  const float* W = (const float*)d_in[2];
  const float* b = (const float*)d_in[3];

  char* ws = (char*)d_ws;
  uint8_t* xb = (uint8_t*)ws;                             // 4,194,304 B
  uint8_t* wb = (uint8_t*)(ws + 4194304);                 // 14,876,672 B (VPAD*512)
  float*   sg = (float*)(ws + 4194304 + 14876672);        // 32 KiB
  float*   py = sg + NROWS;                               // 32 KiB

  prep_kernel<<<11392, 256, 0, stream>>>(x, W, b, y, (int*)xb, (int*)wb, py, sg);
  gemm_stats_kernel<<<dim3(32, 114), 512, 0, stream>>>(xb, wb, b, sg);
  finalize_kernel<<<1, 256, 0, stream>>>(sg, py, (float*)d_out);
}

// Round 5
// 296.876 us; speedup vs baseline: 1.0937x; 1.0937x over previous
//
#include <hip/hip_runtime.h>
#include <stdint.h>

#define VOCAB 28996
#define EMBED 512
#define NROWS 8192
#define VPAD  29056  /* 227 * 128 */
#define LOG2E 1.4426950408889634f
#define WSCALE 16.0f
#define INV_WSCALE_L2E (LOG2E / 16.0f)

typedef __attribute__((ext_vector_type(4)))  int   i32x4;
typedef __attribute__((ext_vector_type(8)))  int   i32x8;
typedef __attribute__((ext_vector_type(16))) float f32x16;

__device__ __forceinline__ void gload_lds16(const void* g, void* l) {
  __builtin_amdgcn_global_load_lds(
      (__attribute__((address_space(1))) const void*)g,
      (__attribute__((address_space(3))) void*)l, 16, 0, 0);
}

// pack 4 floats -> 4 x fp8 e4m3 (OCP, RNE, saturating) in one i32
__device__ __forceinline__ int pk_fp8x4(float a, float b, float c, float d) {
  int r = __builtin_amdgcn_cvt_pk_fp8_f32(a, b, 0, false);
  r = __builtin_amdgcn_cvt_pk_fp8_f32(c, d, r, true);
  return r;
}

// ---- fused prep (IDENTICAL to the harness-verified round-0 kernel) ----
// blocks [0,7264): W   (VPAD*512/8/256 = 7264)
// blocks [7264,9312): x (8192*512/8/256 = 2048)
// blocks [9312,11360): py (1 wave/row, 4 rows/block)
// blocks [11360,11392): zero sg
__global__ void __launch_bounds__(256)
prep_kernel(const float* __restrict__ x, const float* __restrict__ W,
            const float* __restrict__ b, const int* __restrict__ y,
            int* __restrict__ xb, int* __restrict__ wb,
            float* __restrict__ py, float* __restrict__ sg) {
  const int bid = blockIdx.x;
  if (bid < 7264) {                        // ---- cvt W*16 -> fp8 ----
    int i = (bid * 256 + threadIdx.x) * 8; // float index; VK multiple of 8
    const int VK = VOCAB * EMBED;
    int2 o;
    if (i < VK) {
      float4 v0 = *(const float4*)(W + i);
      float4 v1 = *(const float4*)(W + i + 4);
      o.x = pk_fp8x4(v0.x * WSCALE, v0.y * WSCALE, v0.z * WSCALE, v0.w * WSCALE);
      o.y = pk_fp8x4(v1.x * WSCALE, v1.y * WSCALE, v1.z * WSCALE, v1.w * WSCALE);
    } else { o.x = 0; o.y = 0; }
    *(int2*)(wb + i / 4) = o;
  } else if (bid < 9312) {                 // ---- cvt x -> fp8 ----
    int i = ((bid - 7264) * 256 + threadIdx.x) * 8;
    float4 v0 = *(const float4*)(x + i);
    float4 v1 = *(const float4*)(x + i + 4);
    int2 o;
    o.x = pk_fp8x4(v0.x, v0.y, v0.z, v0.w);
    o.y = pk_fp8x4(v1.x, v1.y, v1.z, v1.w);
    *(int2*)(xb + i / 4) = o;
  } else if (bid < 11360) {                // ---- py: e^{x.W[y]+b[y]}, fp32 exact ----
    const int row  = ((bid - 9312) * 256 + threadIdx.x) >> 6;
    const int lane = threadIdx.x & 63;
    const int yr = y[row];
    const float4* xr = (const float4*)(x + (size_t)row * EMBED);
    const float4* wr = (const float4*)(W + (size_t)yr * EMBED);
    float d = 0.f;
#pragma unroll
    for (int t = 0; t < 2; ++t) {
      float4 a = xr[lane * 2 + t], c = wr[lane * 2 + t];
      d += a.x * c.x + a.y * c.y + a.z * c.z + a.w * c.w;
    }
#pragma unroll
    for (int m = 1; m < 64; m <<= 1) d += __shfl_xor(d, m);
    if (lane == 0) py[row] = __expf(d + b[yr]);
  } else {                                 // ---- zero sg ----
    int i = (bid - 11360) * 256 + threadIdx.x;
    sg[i] = 0.f;
  }
}

// ---- fused GEMM (16*logits = x . (16W)^T, MX-fp8 32x32x64) + row-sum exp ----
// Round-0 geometry (proven 176 us): 128x128 tile, 4 waves 2x2, wave tile
// 64x64 = 2x2 of 32x32, grid 64x227.
// ONE schedule change vs round-0: BK=64 DOUBLE-BUFFER so staging always has
// a full compute phase of latency cover (round-0 drained its stage loads at
// the immediately-following __syncthreads — zero cover, every K-step):
//   prologue: stage(buf0, k=0)
//   for kt in 0..7:
//     __syncthreads();            // drains vmcnt (cur buf landed) + lgkm
//     if (kt<7) stage(buf^1, kt+1);   // drained only at NEXT loop-top sync
//     frags + 4 MFMA from buf[cur];
// Same totals per wave as round-0 (32 stage loads, 64 ds_reads, 32 MFMAs,
// 8 barriers) — pure reordering. LDS 2x(8K+8K)=32 KiB, same as round-0,
// so occupancy (~3.3 blocks/CU) is preserved.
// WAR safety: __syncthreads waits each wave's lgkmcnt(0) before the barrier,
// so all reads of a buffer complete before anyone restages into it.
// LDS layout: row = 64 B (4 x 16B chunks), chunk J of row R at
// R*64 + ((J ^ (R&3))*16); staging destination linear for global_load_lds
// with pre-swizzled global source. 4-way read conflict (same floor as r0).
__global__ void __launch_bounds__(256, 4)
gemm_stats_kernel(const uint8_t* __restrict__ xb, const uint8_t* __restrict__ wb,
                  const float* __restrict__ bias, float* __restrict__ sg) {
  __shared__ uint8_t lA[2][128 * 64];
  __shared__ uint8_t lB[2][128 * 64];

  const int tid  = threadIdx.x;
  const int lane = tid & 63;
  const int w    = tid >> 6;       // wave 0..3
  const int l31  = lane & 31;
  const int h    = lane >> 5;      // k-half for 32x32 operands
  const int wr   = (w >> 1) * 64;  // wave row offset in tile
  const int wc   = (w & 1) * 64;   // wave col offset in tile
  const int rowBase = blockIdx.x * 128;  // x rows     (grid.x = 64)
  const int colBase = blockIdx.y * 128;  // vocab cols (grid.y = 227)

  // staging lane mapping: chunk = 16 rows x 64 B; rowInChunk = lane>>2,
  // slot = lane&3, swizzle key = rowInChunk&3; LDS dest linear lane*16.
  const int ric  = lane >> 2;
  const int slt  = ((lane & 3) ^ (ric & 3)) * 16;

  f32x16 acc[2][2];
#pragma unroll
  for (int i = 0; i < 2; ++i)
#pragma unroll
    for (int j = 0; j < 2; ++j)
#pragma unroll
      for (int r = 0; r < 16; ++r) acc[i][j][r] = 0.f;

  auto stage = [&](int buf, int k0) {
#pragma unroll
    for (int t = 0; t < 2; ++t) {
      const int c = w * 2 + t;               // chunk 0..7 (16 rows each)
      gload_lds16(xb + (size_t)(rowBase + c * 16 + ric) * EMBED + k0 + slt,
                  &lA[buf][c * 1024]);
      gload_lds16(wb + (size_t)(colBase + c * 16 + ric) * EMBED + k0 + slt,
                  &lB[buf][c * 1024]);
    }
  };

  stage(0, 0);   // prologue (cold, once per block)

  const int aBase = (wr + l31) * 64;         // ii=0 fragment row base
  const int bBase = (wc + l31) * 64;         // jj=0 fragment row base
  const int c0    = ((h * 2) ^ (l31 & 3)) << 4;  // chunk J0=h*2, swizzled
  const int c1    = c0 ^ 16;                     // chunk J0|1

#pragma unroll
  for (int kt = 0; kt < 8; ++kt) {
    const int cur = kt & 1;
    // gate: vmcnt(0) (cur buf landed; loads had a full compute phase of
    // cover) + lgkmcnt(0) (prev buf reads done) + barrier
    __syncthreads();
    if (kt < 7) stage(cur ^ 1, (kt + 1) * 64);

    i32x8 bq[2];
#pragma unroll
    for (int jj = 0; jj < 2; ++jj) {
      const uint8_t* bp = &lB[cur][bBase + jj * 32 * 64];
      i32x4 lo = *(const i32x4*)(bp + c0);
      i32x4 hi = *(const i32x4*)(bp + c1);
      bq[jj] = __builtin_shufflevector(lo, hi, 0, 1, 2, 3, 4, 5, 6, 7);
    }
#pragma unroll
    for (int ii = 0; ii < 2; ++ii) {
      const uint8_t* ap = &lA[cur][aBase + ii * 32 * 64];
      i32x4 lo = *(const i32x4*)(ap + c0);
      i32x4 hi = *(const i32x4*)(ap + c1);
      i32x8 af = __builtin_shufflevector(lo, hi, 0, 1, 2, 3, 4, 5, 6, 7);
      acc[ii][0] = __builtin_amdgcn_mfma_scale_f32_32x32x64_f8f6f4(
          af, bq[0], acc[ii][0], 0, 0, 0, 0x7F7F7F7F, 0, 0x7F7F7F7F);
      acc[ii][1] = __builtin_amdgcn_mfma_scale_f32_32x32x64_f8f6f4(
          af, bq[1], acc[ii][1], 0, 0, 0, 0x7F7F7F7F, 0, 0x7F7F7F7F);
    }
  }

  // ---- epilogue: s_row += sum_j exp(acc/16 + bias)  (round-0 verbatim) ----
  // 32x32 C/D layout (m74/m101): col = lane&31, row = (reg&3)+8*(reg>>2)+4*h
  float bvl[2];
#pragma unroll
  for (int jj = 0; jj < 2; ++jj) {
    const int col = colBase + wc + jj * 32 + l31;
    bvl[jj] = (col < VOCAB) ? bias[col] * LOG2E : -1e30f;
  }

  float sp[32];  // v = ii*16 + reg
#pragma unroll
  for (int ii = 0; ii < 2; ++ii)
#pragma unroll
    for (int r = 0; r < 16; ++r)
      sp[ii * 16 + r] = exp2f(fmaf(acc[ii][0][r], INV_WSCALE_L2E, bvl[0])) +
                        exp2f(fmaf(acc[ii][1][r], INV_WSCALE_L2E, bvl[1]));

  // stacking reduction over the 32 cols (xor 1..16 stays within the h-half);
  // ends with lane holding the full col-sum for value index v == (lane&31).
  float t1[16];
#pragma unroll
  for (int u = 0; u < 16; ++u) {
    float a = sp[2 * u]     + __shfl_xor(sp[2 * u],     1);
    float b = sp[2 * u + 1] + __shfl_xor(sp[2 * u + 1], 1);
    t1[u] = (l31 & 1) ? b : a;
  }
  float t2[8];
#pragma unroll
  for (int u = 0; u < 8; ++u) {
    float a = t1[2 * u]     + __shfl_xor(t1[2 * u],     2);
    float b = t1[2 * u + 1] + __shfl_xor(t1[2 * u + 1], 2);
    t2[u] = (l31 & 2) ? b : a;
  }
  float t3[4];
#pragma unroll
  for (int u = 0; u < 4; ++u) {
    float a = t2[2 * u]     + __shfl_xor(t2[2 * u],     4);
    float b = t2[2 * u + 1] + __shfl_xor(t2[2 * u + 1], 4);
    t3[u] = (l31 & 4) ? b : a;
  }
  float t4[2];
#pragma unroll
  for (int u = 0; u < 2; ++u) {
    float a = t3[2 * u]     + __shfl_xor(t3[2 * u],     8);
    float b = t3[2 * u + 1] + __shfl_xor(t3[2 * u + 1], 8);
    t4[u] = (l31 & 8) ? b : a;
  }
  {
    float a = t4[0] + __shfl_xor(t4[0], 16);
    float b = t4[1] + __shfl_xor(t4[1], 16);
    float ssum = (l31 & 16) ? b : a;
    const int v = l31;                 // ii = v>>4, reg = v&15
    const int row = rowBase + wr + (v >> 4) * 32 + (v & 3) + 8 * ((v & 15) >> 2) + 4 * h;
    atomicAdd(&sg[row], ssum);
  }
}

// ---- final: loss = log(V+1) - mean(py/s)  (q-term ~7e-10, dropped) ----
__global__ void finalize_kernel(const float* __restrict__ sg, const float* __restrict__ py,
                                float* __restrict__ out) {
  __shared__ float red[256];
  float a = 0.f;
  for (int i = threadIdx.x; i < NROWS; i += 256)
    a += py[i] / sg[i];
  red[threadIdx.x] = a;
  __syncthreads();
  for (int st = 128; st > 0; st >>= 1) {
    if (threadIdx.x < st) red[threadIdx.x] += red[threadIdx.x + st];
    __syncthreads();
  }
  if (threadIdx.x == 0)
    out[0] = logf((float)(VOCAB + 1)) - red[0] * (1.f / (float)NROWS);
}

extern "C" void kernel_launch(void* const* d_in, const int* in_sizes, int n_in,
                              void* d_out, int out_size, void* d_ws, size_t ws_size,
                              hipStream_t stream) {
  const float* x = (const float*)d_in[0];
  const int*   y = (const int*)d_in[1];
  const float* W = (const float*)d_in[2];
  const float* b = (const float*)d_in[3];

  char* ws = (char*)d_ws;
  uint8_t* xb = (uint8_t*)ws;                             // 4,194,304 B
  uint8_t* wb = (uint8_t*)(ws + 4194304);                 // 14,876,672 B
  float*   sg = (float*)(ws + 4194304 + 14876672);        // 32 KiB
  float*   py = sg + NROWS;                               // 32 KiB

  prep_kernel<<<11392, 256, 0, stream>>>(x, W, b, y, (int*)xb, (int*)wb, py, sg);
  gemm_stats_kernel<<<dim3(64, 227), 256, 0, stream>>>(xb, wb, b, sg);
  finalize_kernel<<<1, 256, 0, stream>>>(sg, py, (float*)d_out);
}